// Round 3
// baseline (1487.559 us; speedup 1.0000x reference)
//
#include <hip/hip_runtime.h>
#include <cstdint>
#include <cstddef>

// R2: resubmission of R1 source — R1/R2 benches failed on infra (GPU acquisition
// timeout / never ran). ws_size-guarded two-pass stream + verified fused fallback.

#define N_V   8192
#define F_INN 512
#define F_OUT 64
#define CC    4
#define KSEL  16
#define CAP   128           // two-pass candidate buffer per row; E[cnt]~51, sd~7.1 -> 10.8 sigma headroom
#define FCAP  256           // fused-path LDS candidate cap
#define THRESH 2.5f
#define NROWS (N_V * CC)                 // 32768
#define FILTER_BLOCKS 2048
#define FILTER_THREADS (FILTER_BLOCKS * 256)   // 524288 -> 128 float4 per thread

// ---------------- Kernel: h = x @ W  (fp32, vector ALU) ----------------
__global__ __launch_bounds__(256) void linear_kernel(const float* __restrict__ x,
                                                     const float* __restrict__ W,
                                                     float* __restrict__ h) {
    __shared__ float sx[16 * F_INN];
    const int tid  = threadIdx.x;
    const int row0 = blockIdx.x * 16;

    const float4* x4  = (const float4*)(x + (size_t)row0 * F_INN);
    float4*       sx4 = (float4*)sx;
#pragma unroll
    for (int i = 0; i < 8; ++i) sx4[i * 256 + tid] = x4[i * 256 + tid];
    __syncthreads();

    const int f  = tid & 63;
    const int rg = tid >> 6;
    float acc0 = 0.f, acc1 = 0.f, acc2 = 0.f, acc3 = 0.f;
#pragma unroll 4
    for (int k = 0; k < F_INN; ++k) {
        const float wv = W[k * F_OUT + f];
        acc0 += sx[(rg * 4 + 0) * F_INN + k] * wv;
        acc1 += sx[(rg * 4 + 1) * F_INN + k] * wv;
        acc2 += sx[(rg * 4 + 2) * F_INN + k] * wv;
        acc3 += sx[(rg * 4 + 3) * F_INN + k] * wv;
    }
    float* hp = h + (size_t)(row0 + rg * 4) * F_OUT + f;
    hp[0 * F_OUT] = acc0;
    hp[1 * F_OUT] = acc1;
    hp[2 * F_OUT] = acc2;
    hp[3 * F_OUT] = acc3;
}

// Sortable key: higher value wins; tie -> smaller index wins (matches lax.top_k).
__device__ __forceinline__ unsigned long long make_key(float v, int idx) {
    unsigned u = __float_as_uint(v);
    u = (u & 0x80000000u) ? ~u : (u | 0x80000000u);
    return ((unsigned long long)u << 32) | (unsigned long long)(0xFFFFFFFFu - (unsigned)idx);
}
__device__ __forceinline__ float key_val(unsigned long long k) {
    unsigned u = (unsigned)(k >> 32);
    unsigned bits = (u & 0x80000000u) ? (u & 0x7FFFFFFFu) : ~u;
    return __uint_as_float(bits);
}
__device__ __forceinline__ int key_idx(unsigned long long k) {
    return (int)(0xFFFFFFFFu - (unsigned)(k & 0xFFFFFFFFu));
}

// ---------------- Two-pass path, kernel A: zero the per-row counters ----------------
__global__ __launch_bounds__(256) void zero_cnt_kernel(int* __restrict__ cnt) {
    cnt[blockIdx.x * 256 + threadIdx.x] = 0;
}

// ---------------- Two-pass path, kernel B: streaming threshold filter ----------------
// Pure stream of the 1.07 GB attention matrix; no barriers, no LDS, low VGPR.
__global__ __launch_bounds__(256) void filter_kernel(const float* __restrict__ att,
                                                     int* __restrict__ cnt,
                                                     unsigned long long* __restrict__ cand) {
    const float4* a4 = (const float4*)att;
    const int tId = blockIdx.x * 256 + threadIdx.x;   // 0 .. 524287

#pragma unroll 1
    for (int k = 0; k < 128; k += 4) {
        float4 a[4];
#pragma unroll
        for (int u = 0; u < 4; ++u)
            a[u] = a4[(size_t)(k + u) * FILTER_THREADS + tId];
#pragma unroll
        for (int u = 0; u < 4; ++u) {
            const size_t i = (size_t)(k + u) * FILTER_THREADS + tId;
            const int r     = (int)(i >> 11);         // 2048 float4 per row
            const int cbase = ((int)i & 2047) * 4;
            const float4 v = a[u];
            if (v.x > THRESH) { int p = atomicAdd(&cnt[r], 1); if (p < CAP) cand[(size_t)r * CAP + p] = make_key(v.x, cbase + 0); }
            if (v.y > THRESH) { int p = atomicAdd(&cnt[r], 1); if (p < CAP) cand[(size_t)r * CAP + p] = make_key(v.y, cbase + 1); }
            if (v.z > THRESH) { int p = atomicAdd(&cnt[r], 1); if (p < CAP) cand[(size_t)r * CAP + p] = make_key(v.z, cbase + 2); }
            if (v.w > THRESH) { int p = atomicAdd(&cnt[r], 1); if (p < CAP) cand[(size_t)r * CAP + p] = make_key(v.w, cbase + 3); }
        }
    }
}

// ---------------- Two-pass path, kernel C: top-16 + softmax + weighted gather ----------------
__global__ __launch_bounds__(256) void topk_kernel(const int* __restrict__ cnt,
                                                   const unsigned long long* __restrict__ cand,
                                                   const float* __restrict__ att,
                                                   const float* __restrict__ h,
                                                   float* __restrict__ out) {
    __shared__ unsigned long long s_key[CAP];
    __shared__ int   s_sel_idx[KSEL];
    __shared__ float s_sel_v[KSEL];
    __shared__ float s_sel_e[KSEL];
    __shared__ float s_part[4][F_OUT];

    const int tid = threadIdx.x;
    const int r   = blockIdx.x;
    const int c   = cnt[r];

    if (c >= KSEL && c <= CAP) {
        // Expected-always path (c ~ 51 +/- 7).
        if (tid < c) s_key[tid] = cand[(size_t)r * CAP + tid];
        __syncthreads();
        if (tid < c) {
            const unsigned long long mk = s_key[tid];
            int rank = 0;
            for (int j = 0; j < c; ++j) rank += (s_key[j] > mk);  // strict total order
            if (rank < KSEL) { s_sel_v[rank] = key_val(mk); s_sel_idx[rank] = key_idx(mk); }
        }
        __syncthreads();
    } else {
        // Exact fallback: 16 rounds of bounded block-argmax over the full row.
        __shared__ unsigned long long s_red[256];
        __shared__ unsigned long long s_bound;
        if (tid == 0) s_bound = ~0ull;
        __syncthreads();
        const float4* att4 = (const float4*)(att + (size_t)r * N_V);
        for (int round = 0; round < KSEL; ++round) {
            const unsigned long long bound = s_bound;
            unsigned long long best = 0ull;
            for (int j = 0; j < 8; ++j) {
                const float4 v = att4[j * 256 + tid];
                const int base = (j * 256 + tid) * 4;
                const unsigned long long k0 = make_key(v.x, base + 0);
                const unsigned long long k1 = make_key(v.y, base + 1);
                const unsigned long long k2 = make_key(v.z, base + 2);
                const unsigned long long k3 = make_key(v.w, base + 3);
                if (k0 < bound && k0 > best) best = k0;
                if (k1 < bound && k1 > best) best = k1;
                if (k2 < bound && k2 > best) best = k2;
                if (k3 < bound && k3 > best) best = k3;
            }
            s_red[tid] = best;
            __syncthreads();
            for (int s = 128; s > 0; s >>= 1) {
                if (tid < s && s_red[tid + s] > s_red[tid]) s_red[tid] = s_red[tid + s];
                __syncthreads();
            }
            if (tid == 0) {
                s_sel_v[round]   = key_val(s_red[0]);
                s_sel_idx[round] = key_idx(s_red[0]);
                s_bound = s_red[0];
            }
            __syncthreads();
        }
    }

    if (tid < KSEL) {
        const float m = s_sel_v[0];
        s_sel_e[tid] = expf(s_sel_v[tid] - m);
    }
    __syncthreads();

    float ssum = 0.f;
#pragma unroll
    for (int k = 0; k < KSEL; ++k) ssum += s_sel_e[k];

    const int f = tid & 63;
    const int g = tid >> 6;
    float acc = 0.f;
#pragma unroll
    for (int k = 0; k < 4; ++k) {
        const int kk = g * 4 + k;
        acc += s_sel_e[kk] * h[(size_t)s_sel_idx[kk] * F_OUT + f];
    }
    s_part[g][f] = acc;
    __syncthreads();

    if (g == 0) {
        const float tot = (s_part[0][f] + s_part[1][f] + s_part[2][f] + s_part[3][f]) / ssum;
        const int c2 = r >> 13;
        const int n  = r & (N_V - 1);
        out[(size_t)n * (CC * F_OUT) + c2 * F_OUT + f] = tot;
    }
}

// ---------------- Fallback path: previous session's verified fused kernel ----------------
// Used only if ws_size cannot hold the two-pass candidate buffers. Known-passing, 1384 us.
__global__ __launch_bounds__(256) void topk_spmm_fused_kernel(const float* __restrict__ att,
                                                              const float* __restrict__ h,
                                                              float* __restrict__ out) {
    __shared__ int   s_cnt;
    __shared__ float s_val[FCAP];
    __shared__ int   s_idx[FCAP];
    __shared__ int   s_sel_idx[KSEL];
    __shared__ float s_sel_v[KSEL];
    __shared__ float s_sel_e[KSEL];
    __shared__ float s_part[4][F_OUT];
    __shared__ unsigned long long s_red[256];
    __shared__ unsigned long long s_bound;

    const int tid = threadIdx.x;
    const int r   = blockIdx.x;
    const float4* att4 = (const float4*)(att + (size_t)r * N_V);

    if (tid == 0) s_cnt = 0;
    __syncthreads();

    float4 v[8];
#pragma unroll
    for (int j = 0; j < 8; ++j) v[j] = att4[j * 256 + tid];

#pragma unroll
    for (int j = 0; j < 8; ++j) {
        const int base = (j * 256 + tid) * 4;
        if (v[j].x > THRESH) { int p = atomicAdd(&s_cnt, 1); if (p < FCAP) { s_val[p] = v[j].x; s_idx[p] = base + 0; } }
        if (v[j].y > THRESH) { int p = atomicAdd(&s_cnt, 1); if (p < FCAP) { s_val[p] = v[j].y; s_idx[p] = base + 1; } }
        if (v[j].z > THRESH) { int p = atomicAdd(&s_cnt, 1); if (p < FCAP) { s_val[p] = v[j].z; s_idx[p] = base + 2; } }
        if (v[j].w > THRESH) { int p = atomicAdd(&s_cnt, 1); if (p < FCAP) { s_val[p] = v[j].w; s_idx[p] = base + 3; } }
    }
    __syncthreads();
    const int cnt = s_cnt;

    if (cnt >= KSEL && cnt <= FCAP) {
        if (tid < cnt) {
            const float myv = s_val[tid];
            const int   myi = s_idx[tid];
            int rank = 0;
            for (int j = 0; j < cnt; ++j) {
                const float vj = s_val[j];
                const int   ij = s_idx[j];
                rank += (vj > myv) || (vj == myv && ij < myi);
            }
            if (rank < KSEL) { s_sel_idx[rank] = myi; s_sel_v[rank] = myv; }
        }
        __syncthreads();
    } else {
        if (tid == 0) s_bound = ~0ull;
        __syncthreads();
        for (int round = 0; round < KSEL; ++round) {
            const unsigned long long bound = s_bound;
            unsigned long long best = 0ull;
#pragma unroll
            for (int j = 0; j < 8; ++j) {
                const int base = (j * 256 + tid) * 4;
                unsigned long long k0 = make_key(v[j].x, base + 0);
                unsigned long long k1 = make_key(v[j].y, base + 1);
                unsigned long long k2 = make_key(v[j].z, base + 2);
                unsigned long long k3 = make_key(v[j].w, base + 3);
                if (k0 < bound && k0 > best) best = k0;
                if (k1 < bound && k1 > best) best = k1;
                if (k2 < bound && k2 > best) best = k2;
                if (k3 < bound && k3 > best) best = k3;
            }
            s_red[tid] = best;
            __syncthreads();
            for (int s = 128; s > 0; s >>= 1) {
                if (tid < s && s_red[tid + s] > s_red[tid]) s_red[tid] = s_red[tid + s];
                __syncthreads();
            }
            if (tid == 0) {
                s_sel_v[round]   = key_val(s_red[0]);
                s_sel_idx[round] = key_idx(s_red[0]);
                s_bound = s_red[0];
            }
            __syncthreads();
        }
    }

    if (tid < KSEL) {
        const float m = s_sel_v[0];
        s_sel_e[tid] = expf(s_sel_v[tid] - m);
    }
    __syncthreads();

    float ssum = 0.f;
#pragma unroll
    for (int k = 0; k < KSEL; ++k) ssum += s_sel_e[k];

    const int f = tid & 63;
    const int g = tid >> 6;
    float acc = 0.f;
#pragma unroll
    for (int k = 0; k < 4; ++k) {
        const int kk = g * 4 + k;
        acc += s_sel_e[kk] * h[(size_t)s_sel_idx[kk] * F_OUT + f];
    }
    s_part[g][f] = acc;
    __syncthreads();

    if (g == 0) {
        const float tot = (s_part[0][f] + s_part[1][f] + s_part[2][f] + s_part[3][f]) / ssum;
        const int c = r >> 13;
        const int n = r & (N_V - 1);
        out[(size_t)n * (CC * F_OUT) + c * F_OUT + f] = tot;
    }
}

extern "C" void kernel_launch(void* const* d_in, const int* in_sizes, int n_in,
                              void* d_out, int out_size, void* d_ws, size_t ws_size,
                              hipStream_t stream) {
    const float* x   = (const float*)d_in[0];  // [8192, 512]
    const float* W   = (const float*)d_in[1];  // [512, 64]
    const float* att = (const float*)d_in[2];  // [32768, 8192]
    float*       out = (float*)d_out;          // [8192, 256]

    const size_t H_BYTES    = (size_t)N_V * F_OUT * sizeof(float);       // 2 MB
    const size_t CNT_BYTES  = (size_t)NROWS * sizeof(int);               // 128 KB
    const size_t CAND_BYTES = (size_t)NROWS * CAP * sizeof(unsigned long long); // 32 MB

    float* h = (float*)d_ws;
    linear_kernel<<<N_V / 16, 256, 0, stream>>>(x, W, h);

    if (ws_size >= H_BYTES + CNT_BYTES + CAND_BYTES) {
        // Two-pass: streaming filter at full HBM BW, then cheap exact top-k.
        int*                cnt  = (int*)((char*)d_ws + H_BYTES);
        unsigned long long* cand = (unsigned long long*)((char*)d_ws + H_BYTES + CNT_BYTES);
        zero_cnt_kernel<<<NROWS / 256, 256, 0, stream>>>(cnt);
        filter_kernel<<<FILTER_BLOCKS, 256, 0, stream>>>(att, cnt, cand);
        topk_kernel<<<NROWS, 256, 0, stream>>>(cnt, cand, att, h, out);
    } else {
        // Workspace too small for candidate buffers: verified fused path.
        topk_spmm_fused_kernel<<<NROWS, 256, 0, stream>>>(att, h, out);
    }
}